// Round 1
// baseline (476.609 us; speedup 1.0000x reference)
//
#include <hip/hip_runtime.h>

constexpr int NN  = 50000;
constexpr int NE  = 1600000;
constexpr int CIN = 384;
constexpr int CH  = 128;
constexpr int CO  = 64;

// ---------------- degree / CSR build ----------------

__global__ void count_kernel(const int* __restrict__ dst, int* __restrict__ counts) {
    int i = blockIdx.x * 256 + threadIdx.x;
    if (i < NE) atomicAdd(&counts[dst[i]], 1);
}

__global__ __launch_bounds__(1024) void scan1_kernel(const int* __restrict__ counts,
                                                     int* __restrict__ partial,
                                                     int* __restrict__ blockSums) {
    __shared__ int tmp[1024];
    int t = threadIdx.x;
    int i = blockIdx.x * 1024 + t;
    int v = (i < NN) ? counts[i] : 0;
    tmp[t] = v;
    __syncthreads();
    for (int off = 1; off < 1024; off <<= 1) {
        int add = (t >= off) ? tmp[t - off] : 0;
        __syncthreads();
        tmp[t] += add;
        __syncthreads();
    }
    if (i < NN) partial[i] = tmp[t] - v;   // block-local exclusive scan
    if (t == 1023) blockSums[blockIdx.x] = tmp[1023];
}

__global__ void scan2_kernel(int* __restrict__ blockSums, int nb) {
    if (threadIdx.x == 0 && blockIdx.x == 0) {
        int acc = 0;
        for (int b = 0; b < nb; ++b) { int v = blockSums[b]; blockSums[b] = acc; acc += v; }
    }
}

__global__ void scan3_kernel(const int* __restrict__ counts, int* __restrict__ row_start,
                             int* __restrict__ cursor, float* __restrict__ dinv,
                             const int* __restrict__ blockSums) {
    int i = blockIdx.x * 256 + threadIdx.x;
    if (i < NN) {
        int rs = row_start[i] + blockSums[i >> 10];
        row_start[i] = rs;
        cursor[i] = rs;
        dinv[i] = rsqrtf((float)(counts[i] + 1));  // deg = in-degree + self-loop >= 1
    } else if (i == NN) {
        row_start[NN] = NE;
    }
}

__global__ void scatter_kernel(const int* __restrict__ src, const int* __restrict__ dst,
                               int* __restrict__ cursor, int* __restrict__ csr_src) {
    int i = blockIdx.x * 256 + threadIdx.x;
    if (i < NE) {
        int d = dst[i];
        int pos = atomicAdd(&cursor[d], 1);
        csr_src[pos] = src[i];
    }
}

// ---------------- GEMMs (fp32, tiled) ----------------

__global__ __launch_bounds__(256) void gemm1_kernel(const float* __restrict__ X,
                                                    const float* __restrict__ W,
                                                    float* __restrict__ H) {
    // C[64 x 128] tile, K=384 in chunks of 32
    __shared__ float xs[32][65];    // [k][row] transposed, stride 65 avoids bank conflicts
    __shared__ float ws[32][128];   // [k][col]
    int tid = threadIdx.x;
    int tx = tid & 15, ty = tid >> 4;
    int row0 = blockIdx.x * 64;
    float acc[4][8] = {};
    for (int k0 = 0; k0 < CIN; k0 += 32) {
        int lr = tid >> 2, lc = (tid & 3) * 8;
        int grow = row0 + lr;
        float4 v0 = make_float4(0, 0, 0, 0), v1 = v0;
        if (grow < NN) {
            const float4* xp4 = reinterpret_cast<const float4*>(X + (size_t)grow * CIN + k0 + lc);
            v0 = xp4[0]; v1 = xp4[1];
        }
        xs[lc + 0][lr] = v0.x; xs[lc + 1][lr] = v0.y; xs[lc + 2][lr] = v0.z; xs[lc + 3][lr] = v0.w;
        xs[lc + 4][lr] = v1.x; xs[lc + 5][lr] = v1.y; xs[lc + 6][lr] = v1.z; xs[lc + 7][lr] = v1.w;

        int wr = tid >> 3, wc = (tid & 7) * 16;
        const float4* wp = reinterpret_cast<const float4*>(W + (size_t)(k0 + wr) * CH + wc);
        float4* wsp = reinterpret_cast<float4*>(&ws[wr][wc]);
        wsp[0] = wp[0]; wsp[1] = wp[1]; wsp[2] = wp[2]; wsp[3] = wp[3];
        __syncthreads();
        #pragma unroll
        for (int kk = 0; kk < 32; ++kk) {
            float a[4];
            #pragma unroll
            for (int i = 0; i < 4; ++i) a[i] = xs[kk][ty * 4 + i];
            float4 b0 = *reinterpret_cast<const float4*>(&ws[kk][tx * 8]);
            float4 b1 = *reinterpret_cast<const float4*>(&ws[kk][tx * 8 + 4]);
            float b[8] = {b0.x, b0.y, b0.z, b0.w, b1.x, b1.y, b1.z, b1.w};
            #pragma unroll
            for (int i = 0; i < 4; ++i)
                #pragma unroll
                for (int j = 0; j < 8; ++j)
                    acc[i][j] = fmaf(a[i], b[j], acc[i][j]);
        }
        __syncthreads();
    }
    #pragma unroll
    for (int i = 0; i < 4; ++i) {
        int r = row0 + ty * 4 + i;
        if (r < NN) {
            float* hp = H + (size_t)r * CH + tx * 8;
            reinterpret_cast<float4*>(hp)[0] = make_float4(acc[i][0], acc[i][1], acc[i][2], acc[i][3]);
            reinterpret_cast<float4*>(hp)[1] = make_float4(acc[i][4], acc[i][5], acc[i][6], acc[i][7]);
        }
    }
}

__global__ __launch_bounds__(256) void gemm2_kernel(const float* __restrict__ X,
                                                    const float* __restrict__ W,
                                                    float* __restrict__ H) {
    // C[64 x 64] tile, K=128 in chunks of 32
    __shared__ float xs[32][65];
    __shared__ float ws[32][64];
    int tid = threadIdx.x;
    int tx = tid & 15, ty = tid >> 4;
    int row0 = blockIdx.x * 64;
    float acc[4][4] = {};
    for (int k0 = 0; k0 < CH; k0 += 32) {
        int lr = tid >> 2, lc = (tid & 3) * 8;
        int grow = row0 + lr;
        float4 v0 = make_float4(0, 0, 0, 0), v1 = v0;
        if (grow < NN) {
            const float4* xp4 = reinterpret_cast<const float4*>(X + (size_t)grow * CH + k0 + lc);
            v0 = xp4[0]; v1 = xp4[1];
        }
        xs[lc + 0][lr] = v0.x; xs[lc + 1][lr] = v0.y; xs[lc + 2][lr] = v0.z; xs[lc + 3][lr] = v0.w;
        xs[lc + 4][lr] = v1.x; xs[lc + 5][lr] = v1.y; xs[lc + 6][lr] = v1.z; xs[lc + 7][lr] = v1.w;

        int wr = tid >> 3, wc = (tid & 7) * 8;
        const float4* wp = reinterpret_cast<const float4*>(W + (size_t)(k0 + wr) * CO + wc);
        float4* wsp = reinterpret_cast<float4*>(&ws[wr][wc]);
        wsp[0] = wp[0]; wsp[1] = wp[1];
        __syncthreads();
        #pragma unroll
        for (int kk = 0; kk < 32; ++kk) {
            float a[4];
            #pragma unroll
            for (int i = 0; i < 4; ++i) a[i] = xs[kk][ty * 4 + i];
            float4 b0 = *reinterpret_cast<const float4*>(&ws[kk][tx * 4]);
            float b[4] = {b0.x, b0.y, b0.z, b0.w};
            #pragma unroll
            for (int i = 0; i < 4; ++i)
                #pragma unroll
                for (int j = 0; j < 4; ++j)
                    acc[i][j] = fmaf(a[i], b[j], acc[i][j]);
        }
        __syncthreads();
    }
    #pragma unroll
    for (int i = 0; i < 4; ++i) {
        int r = row0 + ty * 4 + i;
        if (r < NN) {
            float* hp = H + (size_t)r * CO + tx * 4;
            reinterpret_cast<float4*>(hp)[0] = make_float4(acc[i][0], acc[i][1], acc[i][2], acc[i][3]);
        }
    }
}

// ---------------- CSR gather-aggregation ----------------

__global__ __launch_bounds__(128) void agg1_kernel(const float* __restrict__ H,
                                                   const int* __restrict__ row_start,
                                                   const int* __restrict__ csr_src,
                                                   const float* __restrict__ dinv,
                                                   const float* __restrict__ bias,
                                                   float* __restrict__ OUT) {
    int n = blockIdx.x;
    int t = threadIdx.x;
    __shared__ int ssrc[128];
    __shared__ float sw[128];
    float dn = dinv[n];
    float acc = dn * H[(size_t)n * CH + t];   // self-loop (outer dn applied at end)
    int e0 = row_start[n], e1 = row_start[n + 1];
    for (int base = e0; base < e1; base += 128) {
        int m = min(128, e1 - base);
        if (t < m) {
            int s = csr_src[base + t];
            ssrc[t] = s;
            sw[t] = dinv[s];
        }
        __syncthreads();
        for (int j = 0; j < m; ++j)
            acc = fmaf(sw[j], H[(size_t)ssrc[j] * CH + t], acc);
        __syncthreads();
    }
    float o = fmaf(dn, acc, bias[t]);
    OUT[(size_t)n * CH + t] = fmaxf(o, 0.f);   // + bias, ReLU
}

__global__ __launch_bounds__(64) void agg2_kernel(const float* __restrict__ H,
                                                  const int* __restrict__ row_start,
                                                  const int* __restrict__ csr_src,
                                                  const float* __restrict__ dinv,
                                                  const float* __restrict__ bias,
                                                  float* __restrict__ OUT) {
    int n = blockIdx.x;
    int t = threadIdx.x;
    __shared__ int ssrc[64];
    __shared__ float sw[64];
    float dn = dinv[n];
    float acc = dn * H[(size_t)n * CO + t];
    int e0 = row_start[n], e1 = row_start[n + 1];
    for (int base = e0; base < e1; base += 64) {
        int m = min(64, e1 - base);
        if (t < m) {
            int s = csr_src[base + t];
            ssrc[t] = s;
            sw[t] = dinv[s];
        }
        __syncthreads();
        for (int j = 0; j < m; ++j)
            acc = fmaf(sw[j], H[(size_t)ssrc[j] * CO + t], acc);
        __syncthreads();
    }
    OUT[(size_t)n * CO + t] = fmaf(dn, acc, bias[t]);  // no ReLU on final layer
}

// ---------------- launch ----------------

extern "C" void kernel_launch(void* const* d_in, const int* in_sizes, int n_in,
                              void* d_out, int out_size, void* d_ws, size_t ws_size,
                              hipStream_t stream) {
    const float* x  = (const float*)d_in[0];
    const int*   ei = (const int*)d_in[1];
    const float* W1 = (const float*)d_in[2];
    const float* b1 = (const float*)d_in[3];
    const float* W2 = (const float*)d_in[4];
    const float* b2 = (const float*)d_in[5];
    const int* srcI = ei;
    const int* dstI = ei + NE;
    float* out = (float*)d_out;

    char* ws = (char*)d_ws;
    size_t off = 0;
    auto take = [&](size_t bytes) {
        char* p = ws + off;
        off = (off + bytes + 255) & ~(size_t)255;
        return p;
    };
    int*   counts    = (int*)take((size_t)NN * 4);
    int*   row_start = (int*)take((size_t)(NN + 1) * 4);
    int*   cursor    = (int*)take((size_t)NN * 4);
    int*   blockSums = (int*)take(64 * 4);
    float* dinv      = (float*)take((size_t)NN * 4);
    int*   csr_src   = (int*)take((size_t)NE * 4);
    float* h1        = (float*)take((size_t)NN * CH * 4);
    float* g1        = (float*)take((size_t)NN * CH * 4);
    float* h2        = h1;   // reuse: h1 dead after agg1

    hipMemsetAsync(counts, 0, (size_t)NN * 4, stream);
    count_kernel<<<(NE + 255) / 256, 256, 0, stream>>>(dstI, counts);
    scan1_kernel<<<(NN + 1023) / 1024, 1024, 0, stream>>>(counts, row_start, blockSums);
    scan2_kernel<<<1, 64, 0, stream>>>(blockSums, (NN + 1023) / 1024);
    scan3_kernel<<<(NN + 1 + 255) / 256, 256, 0, stream>>>(counts, row_start, cursor, dinv, blockSums);
    scatter_kernel<<<(NE + 255) / 256, 256, 0, stream>>>(srcI, dstI, cursor, csr_src);

    gemm1_kernel<<<(NN + 63) / 64, 256, 0, stream>>>(x, W1, h1);
    agg1_kernel<<<NN, 128, 0, stream>>>(h1, row_start, csr_src, dinv, b1, g1);
    gemm2_kernel<<<(NN + 63) / 64, 256, 0, stream>>>(g1, W2, h2);
    agg2_kernel<<<NN, 64, 0, stream>>>(h2, row_start, csr_src, dinv, b2, out);
}

// Round 2
// 340.721 us; speedup vs baseline: 1.3988x; 1.3988x over previous
//
#include <hip/hip_runtime.h>

constexpr int NN  = 50000;
constexpr int NE  = 1600000;
constexpr int CIN = 384;
constexpr int CH  = 128;
constexpr int CO  = 64;

constexpr int NB = (NN + 255) / 256;              // 196 dst-buckets of 256 nodes
constexpr int GEMM1_TILES  = (NN + 63) / 64;      // 782
constexpr int COUNT_EPB    = 4096;                // 256 thr * 16 edges
constexpr int COUNT_BLOCKS = (NE + COUNT_EPB - 1) / COUNT_EPB;   // 391
constexpr int SCAT_EPB     = 8192;                // 512 thr * 16 edges
constexpr int SCAT_BLOCKS  = (NE + SCAT_EPB - 1) / SCAT_EPB;     // 196

// ---------------- fused degree-count + GEMM1 ----------------
// blocks [0, COUNT_BLOCKS): histogram dst into counts (global atomics)
// blocks [COUNT_BLOCKS, COUNT_BLOCKS+GEMM1_TILES): fp32 tiled GEMM h1 = x @ W1

__global__ __launch_bounds__(256) void fused_count_gemm1(const int* __restrict__ dst,
                                                         int* __restrict__ counts,
                                                         const float* __restrict__ X,
                                                         const float* __restrict__ W,
                                                         float* __restrict__ H) {
    if (blockIdx.x < COUNT_BLOCKS) {
        int e = blockIdx.x * COUNT_EPB + threadIdx.x;
        #pragma unroll
        for (int k = 0; k < 16; ++k, e += 256)
            if (e < NE) atomicAdd(&counts[dst[e]], 1);
        return;
    }
    // ---- GEMM1: C[64 x 128] tile, K=384 in chunks of 32 ----
    __shared__ float xs[32][65];
    __shared__ float ws[32][128];
    int tid = threadIdx.x;
    int tx = tid & 15, ty = tid >> 4;
    int row0 = (blockIdx.x - COUNT_BLOCKS) * 64;
    float acc[4][8] = {};
    for (int k0 = 0; k0 < CIN; k0 += 32) {
        int lr = tid >> 2, lc = (tid & 3) * 8;
        int grow = row0 + lr;
        float4 v0 = make_float4(0, 0, 0, 0), v1 = v0;
        if (grow < NN) {
            const float4* xp4 = reinterpret_cast<const float4*>(X + (size_t)grow * CIN + k0 + lc);
            v0 = xp4[0]; v1 = xp4[1];
        }
        xs[lc + 0][lr] = v0.x; xs[lc + 1][lr] = v0.y; xs[lc + 2][lr] = v0.z; xs[lc + 3][lr] = v0.w;
        xs[lc + 4][lr] = v1.x; xs[lc + 5][lr] = v1.y; xs[lc + 6][lr] = v1.z; xs[lc + 7][lr] = v1.w;

        int wr = tid >> 3, wc = (tid & 7) * 16;
        const float4* wp = reinterpret_cast<const float4*>(W + (size_t)(k0 + wr) * CH + wc);
        float4* wsp = reinterpret_cast<float4*>(&ws[wr][wc]);
        wsp[0] = wp[0]; wsp[1] = wp[1]; wsp[2] = wp[2]; wsp[3] = wp[3];
        __syncthreads();
        #pragma unroll
        for (int kk = 0; kk < 32; ++kk) {
            float a[4];
            #pragma unroll
            for (int i = 0; i < 4; ++i) a[i] = xs[kk][ty * 4 + i];
            float4 b0 = *reinterpret_cast<const float4*>(&ws[kk][tx * 8]);
            float4 b1 = *reinterpret_cast<const float4*>(&ws[kk][tx * 8 + 4]);
            float b[8] = {b0.x, b0.y, b0.z, b0.w, b1.x, b1.y, b1.z, b1.w};
            #pragma unroll
            for (int i = 0; i < 4; ++i)
                #pragma unroll
                for (int j = 0; j < 8; ++j)
                    acc[i][j] = fmaf(a[i], b[j], acc[i][j]);
        }
        __syncthreads();
    }
    #pragma unroll
    for (int i = 0; i < 4; ++i) {
        int r = row0 + ty * 4 + i;
        if (r < NN) {
            float* hp = H + (size_t)r * CH + tx * 8;
            reinterpret_cast<float4*>(hp)[0] = make_float4(acc[i][0], acc[i][1], acc[i][2], acc[i][3]);
            reinterpret_cast<float4*>(hp)[1] = make_float4(acc[i][4], acc[i][5], acc[i][6], acc[i][7]);
        }
    }
}

// ---------------- prefix scan over counts -> row_start ----------------

__global__ __launch_bounds__(1024) void scan1_kernel(const int* __restrict__ counts,
                                                     int* __restrict__ partial,
                                                     int* __restrict__ blockSums) {
    __shared__ int tmp[1024];
    int t = threadIdx.x;
    int i = blockIdx.x * 1024 + t;
    int v = (i < NN) ? counts[i] : 0;
    tmp[t] = v;
    __syncthreads();
    for (int off = 1; off < 1024; off <<= 1) {
        int add = (t >= off) ? tmp[t - off] : 0;
        __syncthreads();
        tmp[t] += add;
        __syncthreads();
    }
    if (i < NN) partial[i] = tmp[t] - v;   // block-local exclusive scan
    if (t == 1023) blockSums[blockIdx.x] = tmp[1023];
}

__global__ void scan2_kernel(int* __restrict__ blockSums, int nb) {
    if (threadIdx.x == 0 && blockIdx.x == 0) {
        int acc = 0;
        for (int b = 0; b < nb; ++b) { int v = blockSums[b]; blockSums[b] = acc; acc += v; }
    }
}

__global__ void scan3_kernel(const int* __restrict__ counts, int* __restrict__ row_start,
                             int* __restrict__ bucket_cursor, float* __restrict__ dinv,
                             const int* __restrict__ blockSums) {
    int i = blockIdx.x * 256 + threadIdx.x;
    if (i < NN) {
        int rs = row_start[i] + blockSums[i >> 10];
        row_start[i] = rs;
        if ((i & 255) == 0) bucket_cursor[i >> 8] = rs;
        dinv[i] = rsqrtf((float)(counts[i] + 1));  // deg = in-degree + self-loop
    } else if (i == NN) {
        row_start[NN] = NE;
    }
}

// ---------------- bucketed scatter (pass B) ----------------
// Bins edges into 196 dst-buckets with per-block run locality so L2 can
// write-combine. Entry: src(16b) | local_dst(8b)<<16 packed in uint32.

__global__ __launch_bounds__(512) void bucket_scatter(const int* __restrict__ src,
                                                      const int* __restrict__ dst,
                                                      int* __restrict__ bucket_cursor,
                                                      unsigned int* __restrict__ pairs) {
    __shared__ int hist[NB];
    __shared__ int base[NB];
    int t = threadIdx.x;
    int e0 = blockIdx.x * SCAT_EPB;
    for (int i = t; i < NB; i += 512) hist[i] = 0;
    __syncthreads();
    int key[16];
    unsigned int pay[16];
    #pragma unroll
    for (int k = 0; k < 16; ++k) {
        int e = e0 + k * 512 + t;
        if (e < NE) {
            int s = src[e], d = dst[e];
            int b = d >> 8;
            int pos = atomicAdd(&hist[b], 1);
            key[k] = b | (pos << 8);
            pay[k] = (unsigned int)s | ((unsigned int)(d & 255) << 16);
        } else {
            key[k] = -1;
        }
    }
    __syncthreads();
    for (int i = t; i < NB; i += 512)
        base[i] = hist[i] ? atomicAdd(&bucket_cursor[i], hist[i]) : 0;
    __syncthreads();
    #pragma unroll
    for (int k = 0; k < 16; ++k) {
        if (key[k] >= 0) {
            int b = key[k] & 255, pos = key[k] >> 8;
            pairs[base[b] + pos] = pay[k];
        }
    }
}

// ---------------- in-bucket sort -> exact CSR (pass C) ----------------
// One block per bucket; LDS cursors (no global atomics); csr_src as uint16.

__global__ __launch_bounds__(1024) void bucket_sort(const unsigned int* __restrict__ pairs,
                                                    const int* __restrict__ row_start,
                                                    unsigned short* __restrict__ csr_src) {
    __shared__ int cur[256];
    int b = blockIdx.x, t = threadIdx.x;
    int n0 = b << 8;
    int p0 = row_start[n0];
    int p1 = (b == NB - 1) ? NE : row_start[n0 + 256];
    if (t < 256) {
        int n = n0 + t;
        cur[t] = (n < NN) ? row_start[n] : NE;
    }
    __syncthreads();
    for (int i = p0 + t; i < p1; i += 1024) {
        unsigned int p = pairs[i];
        int ld = (p >> 16) & 255;
        int pos = atomicAdd(&cur[ld], 1);
        csr_src[pos] = (unsigned short)(p & 0xFFFF);
    }
}

// ---------------- GEMM2 (fp32, tiled) ----------------

__global__ __launch_bounds__(256) void gemm2_kernel(const float* __restrict__ X,
                                                    const float* __restrict__ W,
                                                    float* __restrict__ H) {
    __shared__ float xs[32][65];
    __shared__ float ws[32][64];
    int tid = threadIdx.x;
    int tx = tid & 15, ty = tid >> 4;
    int row0 = blockIdx.x * 64;
    float acc[4][4] = {};
    for (int k0 = 0; k0 < CH; k0 += 32) {
        int lr = tid >> 2, lc = (tid & 3) * 8;
        int grow = row0 + lr;
        float4 v0 = make_float4(0, 0, 0, 0), v1 = v0;
        if (grow < NN) {
            const float4* xp4 = reinterpret_cast<const float4*>(X + (size_t)grow * CH + k0 + lc);
            v0 = xp4[0]; v1 = xp4[1];
        }
        xs[lc + 0][lr] = v0.x; xs[lc + 1][lr] = v0.y; xs[lc + 2][lr] = v0.z; xs[lc + 3][lr] = v0.w;
        xs[lc + 4][lr] = v1.x; xs[lc + 5][lr] = v1.y; xs[lc + 6][lr] = v1.z; xs[lc + 7][lr] = v1.w;

        int wr = tid >> 3, wc = (tid & 7) * 8;
        const float4* wp = reinterpret_cast<const float4*>(W + (size_t)(k0 + wr) * CO + wc);
        float4* wsp = reinterpret_cast<float4*>(&ws[wr][wc]);
        wsp[0] = wp[0]; wsp[1] = wp[1];
        __syncthreads();
        #pragma unroll
        for (int kk = 0; kk < 32; ++kk) {
            float a[4];
            #pragma unroll
            for (int i = 0; i < 4; ++i) a[i] = xs[kk][ty * 4 + i];
            float4 b0 = *reinterpret_cast<const float4*>(&ws[kk][tx * 4]);
            float b[4] = {b0.x, b0.y, b0.z, b0.w};
            #pragma unroll
            for (int i = 0; i < 4; ++i)
                #pragma unroll
                for (int j = 0; j < 4; ++j)
                    acc[i][j] = fmaf(a[i], b[j], acc[i][j]);
        }
        __syncthreads();
    }
    #pragma unroll
    for (int i = 0; i < 4; ++i) {
        int r = row0 + ty * 4 + i;
        if (r < NN) {
            float* hp = H + (size_t)r * CO + tx * 4;
            reinterpret_cast<float4*>(hp)[0] = make_float4(acc[i][0], acc[i][1], acc[i][2], acc[i][3]);
        }
    }
}

// ---------------- CSR gather-aggregation ----------------

__global__ __launch_bounds__(128) void agg1_kernel(const float* __restrict__ H,
                                                   const int* __restrict__ row_start,
                                                   const unsigned short* __restrict__ csr_src,
                                                   const float* __restrict__ dinv,
                                                   const float* __restrict__ bias,
                                                   float* __restrict__ OUT) {
    int n = blockIdx.x;
    int t = threadIdx.x;
    __shared__ int ssrc[128];
    __shared__ float sw[128];
    float dn = dinv[n];
    float acc = dn * H[(size_t)n * CH + t];   // self-loop (outer dn applied at end)
    int e0 = row_start[n], e1 = row_start[n + 1];
    for (int base = e0; base < e1; base += 128) {
        int m = min(128, e1 - base);
        if (t < m) {
            int s = csr_src[base + t];
            ssrc[t] = s;
            sw[t] = dinv[s];
        }
        __syncthreads();
        for (int j = 0; j < m; ++j)
            acc = fmaf(sw[j], H[(size_t)ssrc[j] * CH + t], acc);
        __syncthreads();
    }
    float o = fmaf(dn, acc, bias[t]);
    OUT[(size_t)n * CH + t] = fmaxf(o, 0.f);   // + bias, ReLU
}

__global__ __launch_bounds__(64) void agg2_kernel(const float* __restrict__ H,
                                                  const int* __restrict__ row_start,
                                                  const unsigned short* __restrict__ csr_src,
                                                  const float* __restrict__ dinv,
                                                  const float* __restrict__ bias,
                                                  float* __restrict__ OUT) {
    int n = blockIdx.x;
    int t = threadIdx.x;
    __shared__ int ssrc[64];
    __shared__ float sw[64];
    float dn = dinv[n];
    float acc = dn * H[(size_t)n * CO + t];
    int e0 = row_start[n], e1 = row_start[n + 1];
    for (int base = e0; base < e1; base += 64) {
        int m = min(64, e1 - base);
        if (t < m) {
            int s = csr_src[base + t];
            ssrc[t] = s;
            sw[t] = dinv[s];
        }
        __syncthreads();
        for (int j = 0; j < m; ++j)
            acc = fmaf(sw[j], H[(size_t)ssrc[j] * CO + t], acc);
        __syncthreads();
    }
    OUT[(size_t)n * CO + t] = fmaf(dn, acc, bias[t]);  // no ReLU on final layer
}

// ---------------- launch ----------------

extern "C" void kernel_launch(void* const* d_in, const int* in_sizes, int n_in,
                              void* d_out, int out_size, void* d_ws, size_t ws_size,
                              hipStream_t stream) {
    const float* x  = (const float*)d_in[0];
    const int*   ei = (const int*)d_in[1];
    const float* W1 = (const float*)d_in[2];
    const float* b1 = (const float*)d_in[3];
    const float* W2 = (const float*)d_in[4];
    const float* b2 = (const float*)d_in[5];
    const int* srcI = ei;
    const int* dstI = ei + NE;
    float* out = (float*)d_out;

    char* ws = (char*)d_ws;
    size_t off = 0;
    auto take = [&](size_t bytes) {
        char* p = ws + off;
        off = (off + bytes + 255) & ~(size_t)255;
        return p;
    };
    int*            counts        = (int*)take((size_t)NN * 4);
    int*            row_start     = (int*)take((size_t)(NN + 1) * 4);
    int*            blockSums     = (int*)take(64 * 4);
    int*            bucket_cursor = (int*)take((size_t)NB * 4);
    float*          dinv          = (float*)take((size_t)NN * 4);
    unsigned int*   pairs         = (unsigned int*)take((size_t)NE * 4);
    unsigned short* csr_src       = (unsigned short*)take((size_t)NE * 2);
    float*          h1            = (float*)take((size_t)NN * CH * 4);
    float*          g1            = (float*)take((size_t)NN * CH * 4);
    float*          h2            = h1;   // reuse: h1 dead after agg1

    hipMemsetAsync(counts, 0, (size_t)NN * 4, stream);
    fused_count_gemm1<<<COUNT_BLOCKS + GEMM1_TILES, 256, 0, stream>>>(dstI, counts, x, W1, h1);
    scan1_kernel<<<(NN + 1023) / 1024, 1024, 0, stream>>>(counts, row_start, blockSums);
    scan2_kernel<<<1, 64, 0, stream>>>(blockSums, (NN + 1023) / 1024);
    scan3_kernel<<<(NN + 1 + 255) / 256, 256, 0, stream>>>(counts, row_start, bucket_cursor, dinv, blockSums);
    bucket_scatter<<<SCAT_BLOCKS, 512, 0, stream>>>(srcI, dstI, bucket_cursor, pairs);
    bucket_sort<<<NB, 1024, 0, stream>>>(pairs, row_start, csr_src);

    agg1_kernel<<<NN, 128, 0, stream>>>(h1, row_start, csr_src, dinv, b1, g1);
    gemm2_kernel<<<(NN + 63) / 64, 256, 0, stream>>>(g1, W2, h2);
    agg2_kernel<<<NN, 64, 0, stream>>>(h2, row_start, csr_src, dinv, b2, out);
}

// Round 3
// 302.222 us; speedup vs baseline: 1.5770x; 1.1274x over previous
//
#include <hip/hip_runtime.h>

constexpr int NN  = 50000;
constexpr int NE  = 1600000;
constexpr int CIN = 384;
constexpr int CH  = 128;
constexpr int CO  = 64;

constexpr int NB = (NN + 255) / 256;              // 196 dst-buckets of 256 nodes
constexpr int BUCKET_CAP = 16384;                 // append region per bucket (mean 8163, std ~90)
constexpr int GEMM1_TILES  = (NN + 63) / 64;      // 782
constexpr int SCAT_EPB     = 4096;                // 256 thr * 16 edges
constexpr int SCAT_BLOCKS  = (NE + SCAT_EPB - 1) / SCAT_EPB;     // 391

// ---------------- init per-bucket append cursors ----------------

__global__ void init_cursor(int* __restrict__ bucket_cursor) {
    int t = threadIdx.x;
    if (t < NB) bucket_cursor[t] = t * BUCKET_CAP;
}

// ---------------- fused GEMM1 + bucketed edge scatter ----------------
// blocks [0, SCAT_BLOCKS): bin edges into per-bucket append regions with
//   run locality (LDS hist -> one region reservation per bucket per block).
// blocks [SCAT_BLOCKS, +GEMM1_TILES): fp32 tiled GEMM h1 = x @ W1.

__global__ __launch_bounds__(256) void fused_gemm1_scatter(const int* __restrict__ src,
                                                           const int* __restrict__ dst,
                                                           int* __restrict__ bucket_cursor,
                                                           unsigned int* __restrict__ pairs,
                                                           const float* __restrict__ X,
                                                           const float* __restrict__ W,
                                                           float* __restrict__ H) {
    __shared__ float xs[32][65];
    __shared__ float ws[32][128];
    __shared__ int hist[NB];
    __shared__ int base_s[NB];

    int tid = threadIdx.x;
    if (blockIdx.x < SCAT_BLOCKS) {
        int e0 = blockIdx.x * SCAT_EPB;
        for (int i = tid; i < NB; i += 256) hist[i] = 0;
        __syncthreads();
        int key[16];
        unsigned int pay[16];
        #pragma unroll
        for (int k = 0; k < 16; ++k) {
            int e = e0 + k * 256 + tid;
            if (e < NE) {
                int s = src[e], d = dst[e];
                int b = d >> 8;
                int pos = atomicAdd(&hist[b], 1);
                key[k] = b | (pos << 8);
                pay[k] = (unsigned int)s | ((unsigned int)(d & 255) << 16);
            } else {
                key[k] = -1;
            }
        }
        __syncthreads();
        for (int i = tid; i < NB; i += 256)
            base_s[i] = hist[i] ? atomicAdd(&bucket_cursor[i], hist[i]) : 0;
        __syncthreads();
        #pragma unroll
        for (int k = 0; k < 16; ++k) {
            if (key[k] >= 0) {
                int b = key[k] & 255, pos = key[k] >> 8;
                pairs[base_s[b] + pos] = pay[k];
            }
        }
        return;
    }

    // ---- GEMM1: C[64 x 128] tile, K=384 in chunks of 32 ----
    int tx = tid & 15, ty = tid >> 4;
    int row0 = (blockIdx.x - SCAT_BLOCKS) * 64;
    float acc[4][8] = {};
    for (int k0 = 0; k0 < CIN; k0 += 32) {
        int lr = tid >> 2, lc = (tid & 3) * 8;
        int grow = row0 + lr;
        float4 v0 = make_float4(0, 0, 0, 0), v1 = v0;
        if (grow < NN) {
            const float4* xp4 = reinterpret_cast<const float4*>(X + (size_t)grow * CIN + k0 + lc);
            v0 = xp4[0]; v1 = xp4[1];
        }
        xs[lc + 0][lr] = v0.x; xs[lc + 1][lr] = v0.y; xs[lc + 2][lr] = v0.z; xs[lc + 3][lr] = v0.w;
        xs[lc + 4][lr] = v1.x; xs[lc + 5][lr] = v1.y; xs[lc + 6][lr] = v1.z; xs[lc + 7][lr] = v1.w;

        int wr = tid >> 3, wc = (tid & 7) * 16;
        const float4* wp = reinterpret_cast<const float4*>(W + (size_t)(k0 + wr) * CH + wc);
        float4* wsp = reinterpret_cast<float4*>(&ws[wr][wc]);
        wsp[0] = wp[0]; wsp[1] = wp[1]; wsp[2] = wp[2]; wsp[3] = wp[3];
        __syncthreads();
        #pragma unroll
        for (int kk = 0; kk < 32; ++kk) {
            float a[4];
            #pragma unroll
            for (int i = 0; i < 4; ++i) a[i] = xs[kk][ty * 4 + i];
            // cols {tx*4+j, 64+tx*4+j}: 2-way LDS bank aliasing only (free)
            float4 b0 = *reinterpret_cast<const float4*>(&ws[kk][tx * 4]);
            float4 b1 = *reinterpret_cast<const float4*>(&ws[kk][tx * 4 + 64]);
            float b[8] = {b0.x, b0.y, b0.z, b0.w, b1.x, b1.y, b1.z, b1.w};
            #pragma unroll
            for (int i = 0; i < 4; ++i)
                #pragma unroll
                for (int j = 0; j < 8; ++j)
                    acc[i][j] = fmaf(a[i], b[j], acc[i][j]);
        }
        __syncthreads();
    }
    #pragma unroll
    for (int i = 0; i < 4; ++i) {
        int r = row0 + ty * 4 + i;
        if (r < NN) {
            float* hp = H + (size_t)r * CH;
            reinterpret_cast<float4*>(hp + tx * 4)[0]      = make_float4(acc[i][0], acc[i][1], acc[i][2], acc[i][3]);
            reinterpret_cast<float4*>(hp + 64 + tx * 4)[0] = make_float4(acc[i][4], acc[i][5], acc[i][6], acc[i][7]);
        }
    }
}

// ---------------- bucket totals -> exclusive scan ----------------

__global__ __launch_bounds__(256) void bucket_scan(const int* __restrict__ bucket_cursor,
                                                   int* __restrict__ bucket_start) {
    __shared__ int tmp[256];
    int t = threadIdx.x;
    int v = (t < NB) ? (bucket_cursor[t] - t * BUCKET_CAP) : 0;
    tmp[t] = v;
    __syncthreads();
    for (int off = 1; off < 256; off <<= 1) {
        int add = (t >= off) ? tmp[t - off] : 0;
        __syncthreads();
        tmp[t] += add;
        __syncthreads();
    }
    if (t < NB) bucket_start[t] = tmp[t] - v;
    if (t == NB - 1) bucket_start[NB] = tmp[t];   // == NE
}

// ---------------- in-bucket count + sort -> CSR, row_start, dinv ----------------
// One block per bucket. LDS histogram gives per-node degree (no global
// atomics); in-block scan gives row_start; cursor scatter emits csr_src u16.

__global__ __launch_bounds__(1024) void bucket_sort(const unsigned int* __restrict__ pairs,
                                                    const int* __restrict__ bucket_cursor,
                                                    const int* __restrict__ bucket_start,
                                                    int* __restrict__ row_start,
                                                    float* __restrict__ dinv,
                                                    unsigned short* __restrict__ csr_src) {
    __shared__ int cnt[256];
    __shared__ int pref[256];
    __shared__ int cur[256];
    int b = blockIdx.x, t = threadIdx.x;
    int p0 = b * BUCKET_CAP;
    int ne = bucket_cursor[b] - p0;
    int out0 = bucket_start[b];
    if (t < 256) cnt[t] = 0;
    __syncthreads();
    for (int i = t; i < ne; i += 1024)
        atomicAdd(&cnt[(pairs[p0 + i] >> 16) & 255], 1);
    __syncthreads();
    if (t < 256) pref[t] = cnt[t];
    __syncthreads();
    for (int off = 1; off < 256; off <<= 1) {
        int add = (t < 256 && t >= off) ? pref[t - off] : 0;
        __syncthreads();
        if (t < 256) pref[t] += add;
        __syncthreads();
    }
    if (t < 256) {
        int n = (b << 8) + t;
        if (n < NN) {
            int rs = out0 + pref[t] - cnt[t];
            row_start[n] = rs;
            cur[t] = rs;
            dinv[n] = rsqrtf((float)(cnt[t] + 1));  // + self-loop
        }
    }
    if (b == NB - 1 && t == 0) row_start[NN] = NE;
    __syncthreads();
    for (int i = t; i < ne; i += 1024) {
        unsigned int p = pairs[p0 + i];
        int pos = atomicAdd(&cur[(p >> 16) & 255], 1);
        csr_src[pos] = (unsigned short)(p & 0xFFFF);
    }
}

// ---------------- GEMM2 (fp32, tiled) ----------------

__global__ __launch_bounds__(256) void gemm2_kernel(const float* __restrict__ X,
                                                    const float* __restrict__ W,
                                                    float* __restrict__ H) {
    __shared__ float xs[32][65];
    __shared__ float ws[32][64];
    int tid = threadIdx.x;
    int tx = tid & 15, ty = tid >> 4;
    int row0 = blockIdx.x * 64;
    float acc[4][4] = {};
    for (int k0 = 0; k0 < CH; k0 += 32) {
        int lr = tid >> 2, lc = (tid & 3) * 8;
        int grow = row0 + lr;
        float4 v0 = make_float4(0, 0, 0, 0), v1 = v0;
        if (grow < NN) {
            const float4* xp4 = reinterpret_cast<const float4*>(X + (size_t)grow * CH + k0 + lc);
            v0 = xp4[0]; v1 = xp4[1];
        }
        xs[lc + 0][lr] = v0.x; xs[lc + 1][lr] = v0.y; xs[lc + 2][lr] = v0.z; xs[lc + 3][lr] = v0.w;
        xs[lc + 4][lr] = v1.x; xs[lc + 5][lr] = v1.y; xs[lc + 6][lr] = v1.z; xs[lc + 7][lr] = v1.w;

        int wr = tid >> 3, wc = (tid & 7) * 8;
        const float4* wp = reinterpret_cast<const float4*>(W + (size_t)(k0 + wr) * CO + wc);
        float4* wsp = reinterpret_cast<float4*>(&ws[wr][wc]);
        wsp[0] = wp[0]; wsp[1] = wp[1];
        __syncthreads();
        #pragma unroll
        for (int kk = 0; kk < 32; ++kk) {
            float a[4];
            #pragma unroll
            for (int i = 0; i < 4; ++i) a[i] = xs[kk][ty * 4 + i];
            float4 b0 = *reinterpret_cast<const float4*>(&ws[kk][tx * 4]);
            float b[4] = {b0.x, b0.y, b0.z, b0.w};
            #pragma unroll
            for (int i = 0; i < 4; ++i)
                #pragma unroll
                for (int j = 0; j < 4; ++j)
                    acc[i][j] = fmaf(a[i], b[j], acc[i][j]);
        }
        __syncthreads();
    }
    #pragma unroll
    for (int i = 0; i < 4; ++i) {
        int r = row0 + ty * 4 + i;
        if (r < NN) {
            float* hp = H + (size_t)r * CO + tx * 4;
            reinterpret_cast<float4*>(hp)[0] = make_float4(acc[i][0], acc[i][1], acc[i][2], acc[i][3]);
        }
    }
}

// ---------------- CSR gather-aggregation ----------------

__global__ __launch_bounds__(128) void agg1_kernel(const float* __restrict__ H,
                                                   const int* __restrict__ row_start,
                                                   const unsigned short* __restrict__ csr_src,
                                                   const float* __restrict__ dinv,
                                                   const float* __restrict__ bias,
                                                   float* __restrict__ OUT) {
    int n = blockIdx.x;
    int t = threadIdx.x;
    __shared__ int ssrc[128];
    __shared__ float sw[128];
    float dn = dinv[n];
    float acc0 = dn * H[(size_t)n * CH + t];   // self-loop (outer dn applied at end)
    float acc1 = 0.f;
    int e0 = row_start[n], e1 = row_start[n + 1];
    for (int base = e0; base < e1; base += 128) {
        int m = min(128, e1 - base);
        if (t < m) {
            int s = csr_src[base + t];
            ssrc[t] = s;
            sw[t] = dinv[s];
        }
        __syncthreads();
        int j = 0;
        for (; j + 1 < m; j += 2) {
            acc0 = fmaf(sw[j],     H[(size_t)ssrc[j] * CH + t],     acc0);
            acc1 = fmaf(sw[j + 1], H[(size_t)ssrc[j + 1] * CH + t], acc1);
        }
        if (j < m) acc0 = fmaf(sw[j], H[(size_t)ssrc[j] * CH + t], acc0);
        __syncthreads();
    }
    float o = fmaf(dn, acc0 + acc1, bias[t]);
    OUT[(size_t)n * CH + t] = fmaxf(o, 0.f);   // + bias, ReLU
}

__global__ __launch_bounds__(64) void agg2_kernel(const float* __restrict__ H,
                                                  const int* __restrict__ row_start,
                                                  const unsigned short* __restrict__ csr_src,
                                                  const float* __restrict__ dinv,
                                                  const float* __restrict__ bias,
                                                  float* __restrict__ OUT) {
    int n = blockIdx.x;
    int t = threadIdx.x;
    __shared__ int ssrc[64];
    __shared__ float sw[64];
    float dn = dinv[n];
    float acc0 = dn * H[(size_t)n * CO + t];
    float acc1 = 0.f;
    int e0 = row_start[n], e1 = row_start[n + 1];
    for (int base = e0; base < e1; base += 64) {
        int m = min(64, e1 - base);
        if (t < m) {
            int s = csr_src[base + t];
            ssrc[t] = s;
            sw[t] = dinv[s];
        }
        __syncthreads();
        int j = 0;
        for (; j + 1 < m; j += 2) {
            acc0 = fmaf(sw[j],     H[(size_t)ssrc[j] * CO + t],     acc0);
            acc1 = fmaf(sw[j + 1], H[(size_t)ssrc[j + 1] * CO + t], acc1);
        }
        if (j < m) acc0 = fmaf(sw[j], H[(size_t)ssrc[j] * CO + t], acc0);
        __syncthreads();
    }
    OUT[(size_t)n * CO + t] = fmaf(dn, acc0 + acc1, bias[t]);  // no ReLU on final layer
}

// ---------------- launch ----------------

extern "C" void kernel_launch(void* const* d_in, const int* in_sizes, int n_in,
                              void* d_out, int out_size, void* d_ws, size_t ws_size,
                              hipStream_t stream) {
    const float* x  = (const float*)d_in[0];
    const int*   ei = (const int*)d_in[1];
    const float* W1 = (const float*)d_in[2];
    const float* b1 = (const float*)d_in[3];
    const float* W2 = (const float*)d_in[4];
    const float* b2 = (const float*)d_in[5];
    const int* srcI = ei;
    const int* dstI = ei + NE;
    float* out = (float*)d_out;

    char* ws = (char*)d_ws;
    size_t off = 0;
    auto take = [&](size_t bytes) {
        char* p = ws + off;
        off = (off + bytes + 255) & ~(size_t)255;
        return p;
    };
    int*            row_start     = (int*)take((size_t)(NN + 1) * 4);
    int*            bucket_cursor = (int*)take((size_t)NB * 4);
    int*            bucket_start  = (int*)take((size_t)(NB + 1) * 4);
    float*          dinv          = (float*)take((size_t)NN * 4);
    unsigned short* csr_src       = (unsigned short*)take((size_t)NE * 2);
    float*          h1            = (float*)take((size_t)NN * CH * 4);
    float*          g1            = (float*)take((size_t)NN * CH * 4);
    // pairs aliases g1: pairs dead (after bucket_sort) before agg1 writes g1
    unsigned int*   pairs         = (unsigned int*)g1;   // needs NB*BUCKET_CAP*4 = 12.85 MB <= 25.6 MB
    float*          h2            = h1;                  // reuse: h1 dead after agg1

    init_cursor<<<1, 256, 0, stream>>>(bucket_cursor);
    fused_gemm1_scatter<<<SCAT_BLOCKS + GEMM1_TILES, 256, 0, stream>>>(srcI, dstI, bucket_cursor,
                                                                       pairs, x, W1, h1);
    bucket_scan<<<1, 256, 0, stream>>>(bucket_cursor, bucket_start);
    bucket_sort<<<NB, 1024, 0, stream>>>(pairs, bucket_cursor, bucket_start,
                                         row_start, dinv, csr_src);

    agg1_kernel<<<NN, 128, 0, stream>>>(h1, row_start, csr_src, dinv, b1, g1);
    gemm2_kernel<<<(NN + 63) / 64, 256, 0, stream>>>(g1, W2, h2);
    agg2_kernel<<<NN, 64, 0, stream>>>(h2, row_start, csr_src, dinv, b2, out);
}

// Round 4
// 256.682 us; speedup vs baseline: 1.8568x; 1.1774x over previous
//
#include <hip/hip_runtime.h>

constexpr int NN  = 50000;
constexpr int NE  = 1600000;
constexpr int CIN = 384;
constexpr int CH  = 128;
constexpr int CO  = 64;

constexpr int NB = (NN + 255) / 256;              // 196 dst-buckets of 256 nodes
constexpr int BUCKET_CAP = 16384;                 // append region per bucket (mean 8163)
constexpr int GEMM1_TILES  = (NN + 63) / 64;      // 782
constexpr int SCAT_EPB     = 4096;                // 256 thr * 16 edges
constexpr int SCAT_BLOCKS  = (NE + SCAT_EPB - 1) / SCAT_EPB;     // 391

// ---------------- bf16 helpers ----------------

__device__ inline unsigned short f2bf(float f) {
    union { float f; unsigned int u; } v; v.f = f;
    unsigned int u = v.u + 0x7FFFu + ((v.u >> 16) & 1u);   // round-to-nearest-even
    return (unsigned short)(u >> 16);
}
__device__ inline float bflo(unsigned int u) { return __uint_as_float(u << 16); }
__device__ inline float bfhi(unsigned int u) { return __uint_as_float(u & 0xFFFF0000u); }

// ---------------- init per-bucket append cursors ----------------

__global__ void init_cursor(int* __restrict__ bucket_cursor) {
    int t = threadIdx.x;
    if (t < NB) bucket_cursor[t] = t * BUCKET_CAP;
}

// ---------------- fused GEMM1 + bucketed edge scatter ----------------
// blocks [0, SCAT_BLOCKS): bin edges into per-bucket append regions.
// blocks [SCAT_BLOCKS, +GEMM1_TILES): fp32 GEMM h1 = x @ W1, bf16 output.

__global__ __launch_bounds__(256) void fused_gemm1_scatter(const int* __restrict__ src,
                                                           const int* __restrict__ dst,
                                                           int* __restrict__ bucket_cursor,
                                                           unsigned int* __restrict__ pairs,
                                                           const float* __restrict__ X,
                                                           const float* __restrict__ W,
                                                           unsigned short* __restrict__ Hb) {
    __shared__ float xs[32][65];
    __shared__ float ws[32][128];
    __shared__ int hist[NB];
    __shared__ int base_s[NB];

    int tid = threadIdx.x;
    if (blockIdx.x < SCAT_BLOCKS) {
        int e0 = blockIdx.x * SCAT_EPB;
        for (int i = tid; i < NB; i += 256) hist[i] = 0;
        __syncthreads();
        int key[16];
        unsigned int pay[16];
        #pragma unroll
        for (int k = 0; k < 16; ++k) {
            int e = e0 + k * 256 + tid;
            if (e < NE) {
                int s = src[e], d = dst[e];
                int b = d >> 8;
                int pos = atomicAdd(&hist[b], 1);
                key[k] = b | (pos << 8);
                pay[k] = (unsigned int)s | ((unsigned int)(d & 255) << 16);
            } else {
                key[k] = -1;
            }
        }
        __syncthreads();
        for (int i = tid; i < NB; i += 256)
            base_s[i] = hist[i] ? atomicAdd(&bucket_cursor[i], hist[i]) : 0;
        __syncthreads();
        #pragma unroll
        for (int k = 0; k < 16; ++k) {
            if (key[k] >= 0) {
                int b = key[k] & 255, pos = key[k] >> 8;
                pairs[base_s[b] + pos] = pay[k];
            }
        }
        return;
    }

    // ---- GEMM1: C[64 x 128] tile, K=384 in chunks of 32 ----
    int tx = tid & 15, ty = tid >> 4;
    int row0 = (blockIdx.x - SCAT_BLOCKS) * 64;
    float acc[4][8] = {};
    for (int k0 = 0; k0 < CIN; k0 += 32) {
        int lr = tid >> 2, lc = (tid & 3) * 8;
        int grow = row0 + lr;
        float4 v0 = make_float4(0, 0, 0, 0), v1 = v0;
        if (grow < NN) {
            const float4* xp4 = reinterpret_cast<const float4*>(X + (size_t)grow * CIN + k0 + lc);
            v0 = xp4[0]; v1 = xp4[1];
        }
        xs[lc + 0][lr] = v0.x; xs[lc + 1][lr] = v0.y; xs[lc + 2][lr] = v0.z; xs[lc + 3][lr] = v0.w;
        xs[lc + 4][lr] = v1.x; xs[lc + 5][lr] = v1.y; xs[lc + 6][lr] = v1.z; xs[lc + 7][lr] = v1.w;

        int wr = tid >> 3, wc = (tid & 7) * 16;
        const float4* wp = reinterpret_cast<const float4*>(W + (size_t)(k0 + wr) * CH + wc);
        float4* wsp = reinterpret_cast<float4*>(&ws[wr][wc]);
        wsp[0] = wp[0]; wsp[1] = wp[1]; wsp[2] = wp[2]; wsp[3] = wp[3];
        __syncthreads();
        #pragma unroll
        for (int kk = 0; kk < 32; ++kk) {
            float a[4];
            #pragma unroll
            for (int i = 0; i < 4; ++i) a[i] = xs[kk][ty * 4 + i];
            // cols {tx*4+j, 64+tx*4+j}: 2-way LDS bank aliasing only (free)
            float4 b0 = *reinterpret_cast<const float4*>(&ws[kk][tx * 4]);
            float4 b1 = *reinterpret_cast<const float4*>(&ws[kk][tx * 4 + 64]);
            float b[8] = {b0.x, b0.y, b0.z, b0.w, b1.x, b1.y, b1.z, b1.w};
            #pragma unroll
            for (int i = 0; i < 4; ++i)
                #pragma unroll
                for (int j = 0; j < 8; ++j)
                    acc[i][j] = fmaf(a[i], b[j], acc[i][j]);
        }
        __syncthreads();
    }
    #pragma unroll
    for (int i = 0; i < 4; ++i) {
        int r = row0 + ty * 4 + i;
        if (r < NN) {
            unsigned short* hp = Hb + (size_t)r * CH;
            ushort4 p0 = make_ushort4(f2bf(acc[i][0]), f2bf(acc[i][1]), f2bf(acc[i][2]), f2bf(acc[i][3]));
            ushort4 p1 = make_ushort4(f2bf(acc[i][4]), f2bf(acc[i][5]), f2bf(acc[i][6]), f2bf(acc[i][7]));
            *reinterpret_cast<ushort4*>(hp + tx * 4)      = p0;
            *reinterpret_cast<ushort4*>(hp + 64 + tx * 4) = p1;
        }
    }
}

// ---------------- bucket totals -> exclusive scan ----------------

__global__ __launch_bounds__(256) void bucket_scan(const int* __restrict__ bucket_cursor,
                                                   int* __restrict__ bucket_start) {
    __shared__ int tmp[256];
    int t = threadIdx.x;
    int v = (t < NB) ? (bucket_cursor[t] - t * BUCKET_CAP) : 0;
    tmp[t] = v;
    __syncthreads();
    for (int off = 1; off < 256; off <<= 1) {
        int add = (t >= off) ? tmp[t - off] : 0;
        __syncthreads();
        tmp[t] += add;
        __syncthreads();
    }
    if (t < NB) bucket_start[t] = tmp[t] - v;
    if (t == NB - 1) bucket_start[NB] = tmp[t];   // == NE
}

// ---------------- in-bucket count + sort -> CSR, row_start, dinv ----------------

__global__ __launch_bounds__(1024) void bucket_sort(const unsigned int* __restrict__ pairs,
                                                    const int* __restrict__ bucket_cursor,
                                                    const int* __restrict__ bucket_start,
                                                    int* __restrict__ row_start,
                                                    float* __restrict__ dinv,
                                                    unsigned short* __restrict__ csr_src) {
    __shared__ int cnt[256];
    __shared__ int pref[256];
    __shared__ int cur[256];
    int b = blockIdx.x, t = threadIdx.x;
    int p0 = b * BUCKET_CAP;
    int ne = bucket_cursor[b] - p0;
    int out0 = bucket_start[b];
    if (t < 256) cnt[t] = 0;
    __syncthreads();
    for (int i = t; i < ne; i += 1024)
        atomicAdd(&cnt[(pairs[p0 + i] >> 16) & 255], 1);
    __syncthreads();
    if (t < 256) pref[t] = cnt[t];
    __syncthreads();
    for (int off = 1; off < 256; off <<= 1) {
        int add = (t < 256 && t >= off) ? pref[t - off] : 0;
        __syncthreads();
        if (t < 256) pref[t] += add;
        __syncthreads();
    }
    if (t < 256) {
        int n = (b << 8) + t;
        if (n < NN) {
            int rs = out0 + pref[t] - cnt[t];
            row_start[n] = rs;
            cur[t] = rs;
            dinv[n] = rsqrtf((float)(cnt[t] + 1));  // + self-loop
        }
    }
    if (b == NB - 1 && t == 0) row_start[NN] = NE;
    __syncthreads();
    for (int i = t; i < ne; i += 1024) {
        unsigned int p = pairs[p0 + i];
        int pos = atomicAdd(&cur[(p >> 16) & 255], 1);
        csr_src[pos] = (unsigned short)(p & 0xFFFF);
    }
}

// ---------------- GEMM2 (fp32 compute, bf16 output) ----------------

__global__ __launch_bounds__(256) void gemm2_kernel(const float* __restrict__ X,
                                                    const float* __restrict__ W,
                                                    unsigned short* __restrict__ Hb) {
    __shared__ float xs[32][65];
    __shared__ float ws[32][64];
    int tid = threadIdx.x;
    int tx = tid & 15, ty = tid >> 4;
    int row0 = blockIdx.x * 64;
    float acc[4][4] = {};
    for (int k0 = 0; k0 < CH; k0 += 32) {
        int lr = tid >> 2, lc = (tid & 3) * 8;
        int grow = row0 + lr;
        float4 v0 = make_float4(0, 0, 0, 0), v1 = v0;
        if (grow < NN) {
            const float4* xp4 = reinterpret_cast<const float4*>(X + (size_t)grow * CH + k0 + lc);
            v0 = xp4[0]; v1 = xp4[1];
        }
        xs[lc + 0][lr] = v0.x; xs[lc + 1][lr] = v0.y; xs[lc + 2][lr] = v0.z; xs[lc + 3][lr] = v0.w;
        xs[lc + 4][lr] = v1.x; xs[lc + 5][lr] = v1.y; xs[lc + 6][lr] = v1.z; xs[lc + 7][lr] = v1.w;

        int wr = tid >> 3, wc = (tid & 7) * 8;
        const float4* wp = reinterpret_cast<const float4*>(W + (size_t)(k0 + wr) * CO + wc);
        float4* wsp = reinterpret_cast<float4*>(&ws[wr][wc]);
        wsp[0] = wp[0]; wsp[1] = wp[1];
        __syncthreads();
        #pragma unroll
        for (int kk = 0; kk < 32; ++kk) {
            float a[4];
            #pragma unroll
            for (int i = 0; i < 4; ++i) a[i] = xs[kk][ty * 4 + i];
            float4 b0 = *reinterpret_cast<const float4*>(&ws[kk][tx * 4]);
            float b[4] = {b0.x, b0.y, b0.z, b0.w};
            #pragma unroll
            for (int i = 0; i < 4; ++i)
                #pragma unroll
                for (int j = 0; j < 4; ++j)
                    acc[i][j] = fmaf(a[i], b[j], acc[i][j]);
        }
        __syncthreads();
    }
    #pragma unroll
    for (int i = 0; i < 4; ++i) {
        int r = row0 + ty * 4 + i;
        if (r < NN) {
            ushort4 p = make_ushort4(f2bf(acc[i][0]), f2bf(acc[i][1]), f2bf(acc[i][2]), f2bf(acc[i][3]));
            *reinterpret_cast<ushort4*>(Hb + (size_t)r * CO + tx * 4) = p;
        }
    }
}

// ---------------- CSR gather-aggregation (bf16 features, 1 wave/node) ----------------

__global__ __launch_bounds__(64) void agg1_kernel(const unsigned int* __restrict__ H,   // bf16x2, ld=64
                                                  const int* __restrict__ row_start,
                                                  const unsigned short* __restrict__ csr_src,
                                                  const float* __restrict__ dinv,
                                                  const float* __restrict__ bias,
                                                  float* __restrict__ OUT) {
    int n = blockIdx.x;
    int l = threadIdx.x;                // lane = channel pair {2l, 2l+1}
    float dn = dinv[n];
    unsigned int us = H[n * 64 + l];
    float acc0 = dn * bflo(us), acc1 = dn * bfhi(us);   // self-loop
    float acc2 = 0.f, acc3 = 0.f;
    int e0 = row_start[n], e1 = row_start[n + 1];
    for (int base = e0; base < e1; base += 64) {
        int m = min(64, e1 - base);
        int sv = csr_src[base + min(l, m - 1)];
        float wv = (l < m) ? dinv[sv] : 0.f;
        int j = 0;
        for (; j + 1 < m; j += 2) {
            int s0 = __shfl(sv, j),     s1 = __shfl(sv, j + 1);
            float w0 = __shfl(wv, j),   w1 = __shfl(wv, j + 1);
            unsigned int u0 = H[s0 * 64 + l];
            unsigned int u1 = H[s1 * 64 + l];
            acc0 = fmaf(w0, bflo(u0), acc0); acc1 = fmaf(w0, bfhi(u0), acc1);
            acc2 = fmaf(w1, bflo(u1), acc2); acc3 = fmaf(w1, bfhi(u1), acc3);
        }
        if (j < m) {
            int s0 = __shfl(sv, j);
            float w0 = __shfl(wv, j);
            unsigned int u0 = H[s0 * 64 + l];
            acc0 = fmaf(w0, bflo(u0), acc0); acc1 = fmaf(w0, bfhi(u0), acc1);
        }
    }
    float2 bv = reinterpret_cast<const float2*>(bias)[l];
    float o0 = fmaf(dn, acc0 + acc2, bv.x);
    float o1 = fmaf(dn, acc1 + acc3, bv.y);
    reinterpret_cast<float2*>(OUT)[n * 64 + l] = make_float2(fmaxf(o0, 0.f), fmaxf(o1, 0.f));
}

__global__ __launch_bounds__(64) void agg2_kernel(const unsigned int* __restrict__ H,   // bf16x2, ld=32
                                                  const int* __restrict__ row_start,
                                                  const unsigned short* __restrict__ csr_src,
                                                  const float* __restrict__ dinv,
                                                  const float* __restrict__ bias,
                                                  float* __restrict__ OUT) {
    int n = blockIdx.x;
    int l = threadIdx.x;
    int half = l >> 5;                  // lanes 0-31: even edges, 32-63: odd edges
    int c = l & 31;                     // channel pair {2c, 2c+1}
    float dn = dinv[n];
    unsigned int us = H[n * 32 + c];
    float acc0 = half ? 0.f : dn * bflo(us);
    float acc1 = half ? 0.f : dn * bfhi(us);
    int e0 = row_start[n], e1 = row_start[n + 1];
    for (int base = e0; base < e1; base += 64) {
        int m = min(64, e1 - base);
        int sv = csr_src[base + min(l, m - 1)];
        float wv = (l < m) ? dinv[sv] : 0.f;
        for (int j = 0; j < m; j += 2) {
            int jj = j + half;
            int s = __shfl(sv, min(jj, m - 1));
            float w = __shfl(wv, jj);   // 0 when jj >= m (odd m, half=1)
            unsigned int u = H[s * 32 + c];
            acc0 = fmaf(w, bflo(u), acc0);
            acc1 = fmaf(w, bfhi(u), acc1);
        }
    }
    acc0 += __shfl_xor(acc0, 32);
    acc1 += __shfl_xor(acc1, 32);
    if (l < 32) {
        float2 bv = reinterpret_cast<const float2*>(bias)[c];
        float o0 = fmaf(dn, acc0, bv.x);
        float o1 = fmaf(dn, acc1, bv.y);
        reinterpret_cast<float2*>(OUT)[n * 32 + c] = make_float2(o0, o1);   // no ReLU
    }
}

// ---------------- launch ----------------

extern "C" void kernel_launch(void* const* d_in, const int* in_sizes, int n_in,
                              void* d_out, int out_size, void* d_ws, size_t ws_size,
                              hipStream_t stream) {
    const float* x  = (const float*)d_in[0];
    const int*   ei = (const int*)d_in[1];
    const float* W1 = (const float*)d_in[2];
    const float* b1 = (const float*)d_in[3];
    const float* W2 = (const float*)d_in[4];
    const float* b2 = (const float*)d_in[5];
    const int* srcI = ei;
    const int* dstI = ei + NE;
    float* out = (float*)d_out;

    char* ws = (char*)d_ws;
    size_t off = 0;
    auto take = [&](size_t bytes) {
        char* p = ws + off;
        off = (off + bytes + 255) & ~(size_t)255;
        return p;
    };
    int*            row_start     = (int*)take((size_t)(NN + 1) * 4);
    int*            bucket_cursor = (int*)take((size_t)NB * 4);
    int*            bucket_start  = (int*)take((size_t)(NB + 1) * 4);
    float*          dinv          = (float*)take((size_t)NN * 4);
    unsigned short* csr_src       = (unsigned short*)take((size_t)NE * 2);
    unsigned short* h1b           = (unsigned short*)take((size_t)NN * CH * 2);   // bf16
    float*          g1            = (float*)take((size_t)NN * CH * 4);            // fp32
    unsigned short* h2b           = (unsigned short*)take((size_t)NN * CO * 2);   // bf16
    // pairs aliases g1: pairs dead (after bucket_sort) before agg1 writes g1
    unsigned int*   pairs         = (unsigned int*)g1;   // NB*BUCKET_CAP*4 = 12.85 MB <= 25.6 MB

    init_cursor<<<1, 256, 0, stream>>>(bucket_cursor);
    fused_gemm1_scatter<<<SCAT_BLOCKS + GEMM1_TILES, 256, 0, stream>>>(srcI, dstI, bucket_cursor,
                                                                       pairs, x, W1, h1b);
    bucket_scan<<<1, 256, 0, stream>>>(bucket_cursor, bucket_start);
    bucket_sort<<<NB, 1024, 0, stream>>>(pairs, bucket_cursor, bucket_start,
                                         row_start, dinv, csr_src);

    agg1_kernel<<<NN, 64, 0, stream>>>((const unsigned int*)h1b, row_start, csr_src, dinv, b1, g1);
    gemm2_kernel<<<(NN + 63) / 64, 256, 0, stream>>>(g1, W2, h2b);
    agg2_kernel<<<NN, 64, 0, stream>>>((const unsigned int*)h2b, row_start, csr_src, dinv, b2, out);
}

// Round 5
// 186.516 us; speedup vs baseline: 2.5553x; 1.3762x over previous
//
#include <hip/hip_runtime.h>

constexpr int NN  = 50000;
constexpr int NE  = 1600000;
constexpr int CIN = 384;
constexpr int CH  = 128;
constexpr int CO  = 64;

constexpr int NB = (NN + 255) / 256;              // 196 dst-buckets of 256 nodes
constexpr int BUCKET_CAP = 16384;                 // append region per bucket (mean 8163)
constexpr int SCAT_EPB     = 4096;                // 256 thr * 16 edges
constexpr int SCAT_BLOCKS  = (NE + SCAT_EPB - 1) / SCAT_EPB;     // 391
constexpr int G1_TILES     = (NN + 127) / 128;    // 391 blocks of 128 rows
constexpr int G2_TILES     = (NN + 127) / 128;    // 391

typedef __attribute__((ext_vector_type(8))) short short8;
typedef __attribute__((ext_vector_type(4))) float f32x4;

// ---------------- bf16 helpers ----------------

__device__ inline unsigned short f2bf(float f) {
    union { float f; unsigned int u; } v; v.f = f;
    unsigned int u = v.u + 0x7FFFu + ((v.u >> 16) & 1u);   // round-to-nearest-even
    return (unsigned short)(u >> 16);
}
__device__ inline float bf2f(unsigned short h) { return __uint_as_float((unsigned int)h << 16); }
__device__ inline float bflo(unsigned int u) { return __uint_as_float(u << 16); }
__device__ inline float bfhi(unsigned int u) { return __uint_as_float(u & 0xFFFF0000u); }

// ---------------- W transpose + hi/lo bf16 split (tiny) ----------------

__global__ __launch_bounds__(256) void wprep(const float* __restrict__ W1, const float* __restrict__ W2,
                                             unsigned short* __restrict__ W1t_hi, unsigned short* __restrict__ W1t_lo,
                                             unsigned short* __restrict__ W2t_hi, unsigned short* __restrict__ W2t_lo) {
    int i = blockIdx.x * 256 + threadIdx.x;
    if (i < CIN * CH) {
        int k = i / CH, c = i % CH;
        float v = W1[i];
        unsigned short h = f2bf(v);
        W1t_hi[c * CIN + k] = h;
        W1t_lo[c * CIN + k] = f2bf(v - bf2f(h));
    } else if (i < CIN * CH + CH * CO) {
        int j = i - CIN * CH;
        int k = j / CO, c = j % CO;
        float v = W2[j];
        unsigned short h = f2bf(v);
        W2t_hi[c * CH + k] = h;
        W2t_lo[c * CH + k] = f2bf(v - bf2f(h));
    }
}

// ---------------- init per-bucket append cursors ----------------

__global__ void init_cursor(int* __restrict__ bucket_cursor) {
    int t = threadIdx.x;
    if (t < NB) bucket_cursor[t] = t * BUCKET_CAP;
}

// ---------------- fused MFMA-GEMM1 + bucketed edge scatter ----------------
// blocks [0, SCAT_BLOCKS): bin edges into per-bucket append regions.
// blocks [SCAT_BLOCKS, +G1_TILES): h1 = x @ W1 via bf16 hi/lo MFMA, bf16 out.

__global__ __launch_bounds__(256) void fused_gemm1_scatter(const int* __restrict__ src,
                                                           const int* __restrict__ dst,
                                                           int* __restrict__ bucket_cursor,
                                                           unsigned int* __restrict__ pairs,
                                                           const float* __restrict__ X,
                                                           const unsigned short* __restrict__ Wt_hi,
                                                           const unsigned short* __restrict__ Wt_lo,
                                                           unsigned short* __restrict__ Hb) {
    __shared__ unsigned short xs_hi[128][40];   // [row][k], stride 40 -> 2-way bank alias (free)
    __shared__ unsigned short xs_lo[128][40];
    __shared__ unsigned short ws_hi[128][40];   // [col][k]
    __shared__ unsigned short ws_lo[128][40];
    __shared__ int hist[NB];
    __shared__ int base_s[NB];

    int tid = threadIdx.x;
    if (blockIdx.x < SCAT_BLOCKS) {
        int e0 = blockIdx.x * SCAT_EPB;
        for (int i = tid; i < NB; i += 256) hist[i] = 0;
        __syncthreads();
        int key[16];
        unsigned int pay[16];
        #pragma unroll
        for (int k = 0; k < 16; ++k) {
            int e = e0 + k * 256 + tid;
            if (e < NE) {
                int s = src[e], d = dst[e];
                int b = d >> 8;
                int pos = atomicAdd(&hist[b], 1);
                key[k] = b | (pos << 8);
                pay[k] = (unsigned int)s | ((unsigned int)(d & 255) << 16);
            } else {
                key[k] = -1;
            }
        }
        __syncthreads();
        for (int i = tid; i < NB; i += 256)
            base_s[i] = hist[i] ? atomicAdd(&bucket_cursor[i], hist[i]) : 0;
        __syncthreads();
        #pragma unroll
        for (int k = 0; k < 16; ++k) {
            if (key[k] >= 0) {
                int b = key[k] & 255, pos = key[k] >> 8;
                pairs[base_s[b] + pos] = pay[k];
            }
        }
        return;
    }

    // ---- GEMM1: 128 rows x 128 cols per block, 4 waves x (32r x 128c) ----
    int wid = tid >> 6, lane = tid & 63;
    int row0 = (blockIdx.x - SCAT_BLOCKS) * 128;
    f32x4 acc[2][8] = {};

    for (int k0 = 0; k0 < CIN; k0 += 32) {
        // stage x tile (fp32 -> bf16 hi/lo): thread = (row, half), 16 floats
        {
            int row = tid >> 1, c = (tid & 1) * 16;
            int grow = row0 + row;
            float f[16];
            if (grow < NN) {
                const float4* p = reinterpret_cast<const float4*>(X + (size_t)grow * CIN + k0 + c);
                float4 v0 = p[0], v1 = p[1], v2 = p[2], v3 = p[3];
                f[0]=v0.x; f[1]=v0.y; f[2]=v0.z; f[3]=v0.w;
                f[4]=v1.x; f[5]=v1.y; f[6]=v1.z; f[7]=v1.w;
                f[8]=v2.x; f[9]=v2.y; f[10]=v2.z; f[11]=v2.w;
                f[12]=v3.x; f[13]=v3.y; f[14]=v3.z; f[15]=v3.w;
            } else {
                #pragma unroll
                for (int i = 0; i < 16; ++i) f[i] = 0.f;
            }
            short8 vh0, vh1, vl0, vl1;
            #pragma unroll
            for (int i = 0; i < 8; ++i) {
                unsigned short h = f2bf(f[i]);
                vh0[i] = (short)h; vl0[i] = (short)f2bf(f[i] - bf2f(h));
            }
            #pragma unroll
            for (int i = 0; i < 8; ++i) {
                unsigned short h = f2bf(f[8 + i]);
                vh1[i] = (short)h; vl1[i] = (short)f2bf(f[8 + i] - bf2f(h));
            }
            *reinterpret_cast<short8*>(&xs_hi[row][c])     = vh0;
            *reinterpret_cast<short8*>(&xs_hi[row][c + 8]) = vh1;
            *reinterpret_cast<short8*>(&xs_lo[row][c])     = vl0;
            *reinterpret_cast<short8*>(&xs_lo[row][c + 8]) = vl1;
        }
        // stage W tile from pre-transposed bf16: 512 16B-chunks per matrix
        {
            #pragma unroll
            for (int p = 0; p < 2; ++p) {
                int ch = tid + p * 256;
                int col = ch >> 2, ko = (ch & 3) * 8;
                *reinterpret_cast<short8*>(&ws_hi[col][ko]) =
                    *reinterpret_cast<const short8*>(Wt_hi + (size_t)col * CIN + k0 + ko);
                *reinterpret_cast<short8*>(&ws_lo[col][ko]) =
                    *reinterpret_cast<const short8*>(Wt_lo + (size_t)col * CIN + k0 + ko);
            }
        }
        __syncthreads();
        int r = lane & 15, ko = (lane >> 4) * 8;
        short8 a_hi[2], a_lo[2];
        #pragma unroll
        for (int rt = 0; rt < 2; ++rt) {
            a_hi[rt] = *reinterpret_cast<const short8*>(&xs_hi[wid * 32 + rt * 16 + r][ko]);
            a_lo[rt] = *reinterpret_cast<const short8*>(&xs_lo[wid * 32 + rt * 16 + r][ko]);
        }
        #pragma unroll
        for (int ct = 0; ct < 8; ++ct) {
            short8 b_hi = *reinterpret_cast<const short8*>(&ws_hi[ct * 16 + r][ko]);
            short8 b_lo = *reinterpret_cast<const short8*>(&ws_lo[ct * 16 + r][ko]);
            #pragma unroll
            for (int rt = 0; rt < 2; ++rt) {
                acc[rt][ct] = __builtin_amdgcn_mfma_f32_16x16x32_bf16(a_hi[rt], b_hi, acc[rt][ct], 0, 0, 0);
                acc[rt][ct] = __builtin_amdgcn_mfma_f32_16x16x32_bf16(a_hi[rt], b_lo, acc[rt][ct], 0, 0, 0);
                acc[rt][ct] = __builtin_amdgcn_mfma_f32_16x16x32_bf16(a_lo[rt], b_hi, acc[rt][ct], 0, 0, 0);
            }
        }
        __syncthreads();
    }
    // epilogue: D row=(lane>>4)*4+j, col=lane&15 per 16x16 tile
    int cl = lane & 15, rg = lane >> 4;
    #pragma unroll
    for (int rt = 0; rt < 2; ++rt) {
        #pragma unroll
        for (int j = 0; j < 4; ++j) {
            int row = row0 + wid * 32 + rt * 16 + rg * 4 + j;
            if (row < NN) {
                unsigned short* hp = Hb + (size_t)row * CH + cl;
                #pragma unroll
                for (int ct = 0; ct < 8; ++ct)
                    hp[ct * 16] = f2bf(acc[rt][ct][j]);
            }
        }
    }
}

// ---------------- bucket totals -> exclusive scan ----------------

__global__ __launch_bounds__(256) void bucket_scan(const int* __restrict__ bucket_cursor,
                                                   int* __restrict__ bucket_start) {
    __shared__ int tmp[256];
    int t = threadIdx.x;
    int v = (t < NB) ? (bucket_cursor[t] - t * BUCKET_CAP) : 0;
    tmp[t] = v;
    __syncthreads();
    for (int off = 1; off < 256; off <<= 1) {
        int add = (t >= off) ? tmp[t - off] : 0;
        __syncthreads();
        tmp[t] += add;
        __syncthreads();
    }
    if (t < NB) bucket_start[t] = tmp[t] - v;
    if (t == NB - 1) bucket_start[NB] = tmp[t];   // == NE
}

// ---------------- in-bucket count + sort -> CSR, row_start, dinv ----------------

__global__ __launch_bounds__(1024) void bucket_sort(const unsigned int* __restrict__ pairs,
                                                    const int* __restrict__ bucket_cursor,
                                                    const int* __restrict__ bucket_start,
                                                    int* __restrict__ row_start,
                                                    float* __restrict__ dinv,
                                                    unsigned short* __restrict__ csr_src) {
    __shared__ int cnt[256];
    __shared__ int pref[256];
    __shared__ int cur[256];
    int b = blockIdx.x, t = threadIdx.x;
    int p0 = b * BUCKET_CAP;
    int ne = bucket_cursor[b] - p0;
    int out0 = bucket_start[b];
    if (t < 256) cnt[t] = 0;
    __syncthreads();
    for (int i = t; i < ne; i += 1024)
        atomicAdd(&cnt[(pairs[p0 + i] >> 16) & 255], 1);
    __syncthreads();
    if (t < 256) pref[t] = cnt[t];
    __syncthreads();
    for (int off = 1; off < 256; off <<= 1) {
        int add = (t < 256 && t >= off) ? pref[t - off] : 0;
        __syncthreads();
        if (t < 256) pref[t] += add;
        __syncthreads();
    }
    if (t < 256) {
        int n = (b << 8) + t;
        if (n < NN) {
            int rs = out0 + pref[t] - cnt[t];
            row_start[n] = rs;
            cur[t] = rs;
            dinv[n] = rsqrtf((float)(cnt[t] + 1));  // + self-loop
        }
    }
    if (b == NB - 1 && t == 0) row_start[NN] = NE;
    __syncthreads();
    for (int i = t; i < ne; i += 1024) {
        unsigned int p = pairs[p0 + i];
        int pos = atomicAdd(&cur[(p >> 16) & 255], 1);
        csr_src[pos] = (unsigned short)(p & 0xFFFF);
    }
}

// ---------------- MFMA GEMM2: h2 = g1 @ W2, bf16 out ----------------

__global__ __launch_bounds__(256) void gemm2_kernel(const float* __restrict__ X,
                                                    const unsigned short* __restrict__ Wt_hi,
                                                    const unsigned short* __restrict__ Wt_lo,
                                                    unsigned short* __restrict__ Hb) {
    __shared__ unsigned short xs_hi[128][40];
    __shared__ unsigned short xs_lo[128][40];
    __shared__ unsigned short ws_hi[64][40];
    __shared__ unsigned short ws_lo[64][40];

    int tid = threadIdx.x;
    int wid = tid >> 6, lane = tid & 63;
    int row0 = blockIdx.x * 128;
    f32x4 acc[2][4] = {};

    for (int k0 = 0; k0 < CH; k0 += 32) {
        {
            int row = tid >> 1, c = (tid & 1) * 16;
            int grow = row0 + row;
            float f[16];
            if (grow < NN) {
                const float4* p = reinterpret_cast<const float4*>(X + (size_t)grow * CH + k0 + c);
                float4 v0 = p[0], v1 = p[1], v2 = p[2], v3 = p[3];
                f[0]=v0.x; f[1]=v0.y; f[2]=v0.z; f[3]=v0.w;
                f[4]=v1.x; f[5]=v1.y; f[6]=v1.z; f[7]=v1.w;
                f[8]=v2.x; f[9]=v2.y; f[10]=v2.z; f[11]=v2.w;
                f[12]=v3.x; f[13]=v3.y; f[14]=v3.z; f[15]=v3.w;
            } else {
                #pragma unroll
                for (int i = 0; i < 16; ++i) f[i] = 0.f;
            }
            short8 vh0, vh1, vl0, vl1;
            #pragma unroll
            for (int i = 0; i < 8; ++i) {
                unsigned short h = f2bf(f[i]);
                vh0[i] = (short)h; vl0[i] = (short)f2bf(f[i] - bf2f(h));
            }
            #pragma unroll
            for (int i = 0; i < 8; ++i) {
                unsigned short h = f2bf(f[8 + i]);
                vh1[i] = (short)h; vl1[i] = (short)f2bf(f[8 + i] - bf2f(h));
            }
            *reinterpret_cast<short8*>(&xs_hi[row][c])     = vh0;
            *reinterpret_cast<short8*>(&xs_hi[row][c + 8]) = vh1;
            *reinterpret_cast<short8*>(&xs_lo[row][c])     = vl0;
            *reinterpret_cast<short8*>(&xs_lo[row][c + 8]) = vl1;
        }
        if (tid < 256) {   // 64 cols x 4 chunks = 256 chunks, 1 per thread
            int col = tid >> 2, ko = (tid & 3) * 8;
            *reinterpret_cast<short8*>(&ws_hi[col][ko]) =
                *reinterpret_cast<const short8*>(Wt_hi + (size_t)col * CH + k0 + ko);
            *reinterpret_cast<short8*>(&ws_lo[col][ko]) =
                *reinterpret_cast<const short8*>(Wt_lo + (size_t)col * CH + k0 + ko);
        }
        __syncthreads();
        int r = lane & 15, ko = (lane >> 4) * 8;
        short8 a_hi[2], a_lo[2];
        #pragma unroll
        for (int rt = 0; rt < 2; ++rt) {
            a_hi[rt] = *reinterpret_cast<const short8*>(&xs_hi[wid * 32 + rt * 16 + r][ko]);
            a_lo[rt] = *reinterpret_cast<const short8*>(&xs_lo[wid * 32 + rt * 16 + r][ko]);
        }
        #pragma unroll
        for (int ct = 0; ct < 4; ++ct) {
            short8 b_hi = *reinterpret_cast<const short8*>(&ws_hi[ct * 16 + r][ko]);
            short8 b_lo = *reinterpret_cast<const short8*>(&ws_lo[ct * 16 + r][ko]);
            #pragma unroll
            for (int rt = 0; rt < 2; ++rt) {
                acc[rt][ct] = __builtin_amdgcn_mfma_f32_16x16x32_bf16(a_hi[rt], b_hi, acc[rt][ct], 0, 0, 0);
                acc[rt][ct] = __builtin_amdgcn_mfma_f32_16x16x32_bf16(a_hi[rt], b_lo, acc[rt][ct], 0, 0, 0);
                acc[rt][ct] = __builtin_amdgcn_mfma_f32_16x16x32_bf16(a_lo[rt], b_hi, acc[rt][ct], 0, 0, 0);
            }
        }
        __syncthreads();
    }
    int cl = lane & 15, rg = lane >> 4;
    #pragma unroll
    for (int rt = 0; rt < 2; ++rt) {
        #pragma unroll
        for (int j = 0; j < 4; ++j) {
            int row = row0 + wid * 32 + rt * 16 + rg * 4 + j;
            if (row < NN) {
                unsigned short* hp = Hb + (size_t)row * CO + cl;
                #pragma unroll
                for (int ct = 0; ct < 4; ++ct)
                    hp[ct * 16] = f2bf(acc[rt][ct][j]);
            }
        }
    }
}

// ---------------- CSR gather-aggregation (bf16 features, 1 wave/node) ----------------

__global__ __launch_bounds__(64) void agg1_kernel(const unsigned int* __restrict__ H,   // bf16x2, ld=64
                                                  const int* __restrict__ row_start,
                                                  const unsigned short* __restrict__ csr_src,
                                                  const float* __restrict__ dinv,
                                                  const float* __restrict__ bias,
                                                  float* __restrict__ OUT) {
    int n = blockIdx.x;
    int l = threadIdx.x;                // lane = channel pair {2l, 2l+1}
    float dn = dinv[n];
    unsigned int us = H[n * 64 + l];
    float acc0 = dn * bflo(us), acc1 = dn * bfhi(us);   // self-loop
    float acc2 = 0.f, acc3 = 0.f;
    int e0 = row_start[n], e1 = row_start[n + 1];
    for (int base = e0; base < e1; base += 64) {
        int m = min(64, e1 - base);
        int sv = csr_src[base + min(l, m - 1)];
        float wv = (l < m) ? dinv[sv] : 0.f;
        int j = 0;
        for (; j + 1 < m; j += 2) {
            int s0 = __shfl(sv, j),     s1 = __shfl(sv, j + 1);
            float w0 = __shfl(wv, j),   w1 = __shfl(wv, j + 1);
            unsigned int u0 = H[s0 * 64 + l];
            unsigned int u1 = H[s1 * 64 + l];
            acc0 = fmaf(w0, bflo(u0), acc0); acc1 = fmaf(w0, bfhi(u0), acc1);
            acc2 = fmaf(w1, bflo(u1), acc2); acc3 = fmaf(w1, bfhi(u1), acc3);
        }
        if (j < m) {
            int s0 = __shfl(sv, j);
            float w0 = __shfl(wv, j);
            unsigned int u0 = H[s0 * 64 + l];
            acc0 = fmaf(w0, bflo(u0), acc0); acc1 = fmaf(w0, bfhi(u0), acc1);
        }
    }
    float2 bv = reinterpret_cast<const float2*>(bias)[l];
    float o0 = fmaf(dn, acc0 + acc2, bv.x);
    float o1 = fmaf(dn, acc1 + acc3, bv.y);
    reinterpret_cast<float2*>(OUT)[n * 64 + l] = make_float2(fmaxf(o0, 0.f), fmaxf(o1, 0.f));
}

__global__ __launch_bounds__(64) void agg2_kernel(const unsigned int* __restrict__ H,   // bf16x2, ld=32
                                                  const int* __restrict__ row_start,
                                                  const unsigned short* __restrict__ csr_src,
                                                  const float* __restrict__ dinv,
                                                  const float* __restrict__ bias,
                                                  float* __restrict__ OUT) {
    int n = blockIdx.x;
    int l = threadIdx.x;
    int half = l >> 5;                  // lanes 0-31: even edges, 32-63: odd edges
    int c = l & 31;                     // channel pair {2c, 2c+1}
    float dn = dinv[n];
    unsigned int us = H[n * 32 + c];
    float acc0 = half ? 0.f : dn * bflo(us);
    float acc1 = half ? 0.f : dn * bfhi(us);
    int e0 = row_start[n], e1 = row_start[n + 1];
    for (int base = e0; base < e1; base += 64) {
        int m = min(64, e1 - base);
        int sv = csr_src[base + min(l, m - 1)];
        float wv = (l < m) ? dinv[sv] : 0.f;
        for (int j = 0; j < m; j += 2) {
            int jj = j + half;
            int s = __shfl(sv, min(jj, m - 1));
            float w = __shfl(wv, jj);   // 0 when jj >= m (odd m, half=1)
            unsigned int u = H[s * 32 + c];
            acc0 = fmaf(w, bflo(u), acc0);
            acc1 = fmaf(w, bfhi(u), acc1);
        }
    }
    acc0 += __shfl_xor(acc0, 32);
    acc1 += __shfl_xor(acc1, 32);
    if (l < 32) {
        float2 bv = reinterpret_cast<const float2*>(bias)[c];
        float o0 = fmaf(dn, acc0, bv.x);
        float o1 = fmaf(dn, acc1, bv.y);
        reinterpret_cast<float2*>(OUT)[n * 32 + c] = make_float2(o0, o1);   // no ReLU
    }
}

// ---------------- launch ----------------

extern "C" void kernel_launch(void* const* d_in, const int* in_sizes, int n_in,
                              void* d_out, int out_size, void* d_ws, size_t ws_size,
                              hipStream_t stream) {
    const float* x  = (const float*)d_in[0];
    const int*   ei = (const int*)d_in[1];
    const float* W1 = (const float*)d_in[2];
    const float* b1 = (const float*)d_in[3];
    const float* W2 = (const float*)d_in[4];
    const float* b2 = (const float*)d_in[5];
    const int* srcI = ei;
    const int* dstI = ei + NE;
    float* out = (float*)d_out;

    char* ws = (char*)d_ws;
    size_t off = 0;
    auto take = [&](size_t bytes) {
        char* p = ws + off;
        off = (off + bytes + 255) & ~(size_t)255;
        return p;
    };
    int*            row_start     = (int*)take((size_t)(NN + 1) * 4);
    int*            bucket_cursor = (int*)take((size_t)NB * 4);
    int*            bucket_start  = (int*)take((size_t)(NB + 1) * 4);
    float*          dinv          = (float*)take((size_t)NN * 4);
    unsigned short* W1t_hi        = (unsigned short*)take((size_t)CH * CIN * 2);
    unsigned short* W1t_lo        = (unsigned short*)take((size_t)CH * CIN * 2);
    unsigned short* W2t_hi        = (unsigned short*)take((size_t)CO * CH * 2);
    unsigned short* W2t_lo        = (unsigned short*)take((size_t)CO * CH * 2);
    unsigned short* csr_src       = (unsigned short*)take((size_t)NE * 2);
    unsigned short* h1b           = (unsigned short*)take((size_t)NN * CH * 2);   // bf16
    float*          g1            = (float*)take((size_t)NN * CH * 4);            // fp32
    unsigned short* h2b           = (unsigned short*)take((size_t)NN * CO * 2);   // bf16
    // pairs aliases g1: pairs dead (after bucket_sort) before agg1 writes g1
    unsigned int*   pairs         = (unsigned int*)g1;   // NB*BUCKET_CAP*4 = 12.85 MB <= 25.6 MB

    wprep<<<(CIN * CH + CH * CO + 255) / 256, 256, 0, stream>>>(W1, W2, W1t_hi, W1t_lo, W2t_hi, W2t_lo);
    init_cursor<<<1, 256, 0, stream>>>(bucket_cursor);
    fused_gemm1_scatter<<<SCAT_BLOCKS + G1_TILES, 256, 0, stream>>>(srcI, dstI, bucket_cursor,
                                                                    pairs, x, W1t_hi, W1t_lo, h1b);
    bucket_scan<<<1, 256, 0, stream>>>(bucket_cursor, bucket_start);
    bucket_sort<<<NB, 1024, 0, stream>>>(pairs, bucket_cursor, bucket_start,
                                         row_start, dinv, csr_src);

    agg1_kernel<<<NN, 64, 0, stream>>>((const unsigned int*)h1b, row_start, csr_src, dinv, b1, g1);
    gemm2_kernel<<<G2_TILES, 256, 0, stream>>>(g1, W2t_hi, W2t_lo, h2b);
    agg2_kernel<<<NN, 64, 0, stream>>>((const unsigned int*)h2b, row_start, csr_src, dinv, b2, out);
}